// Round 9
// baseline (341.530 us; speedup 1.0000x reference)
//
#include <hip/hip_runtime.h>

// LoRAConnector: B=4, T=2048, N=4, C=1024, A=8, nC=4096, SINKHORN_ITERS=20
//
// Round 10: barrier-free kernel A — phi direct from cache, no LDS staging.
//  R8 ablation: A (reduction) = 104us is the whole target; B ~40us ~= its
//  256MB floor. A's VALU floor ~15-20us, x-stream ~25us -> ~60us stall from
//  the per-tile __syncthreads vmcnt(0) drain of the mid-iter x prefetch.
//  Key insight: LDS staging only bought phi dedup, but the half-split
//  decomposition already dedups phi across tokens IN REGISTERS, and phi is
//  L2-resident (384KB/adapter, shared by all blocks of a batch). The pr
//  stride-64B access is line-exact (q=0..3 of one d = one 64B line), L1
//  cached, 4x reused per block. Staging was pure overhead (Common-mistake
//  #7, attn m169 lesson). So: delete tileL + global_load_lds + all phase-1
//  barriers. TLP hides latency: LDS -> 0.9KB, occupancy VGPR-capped; live
//  ~= 52 acc + 17 prefetch/loads + addr ~= 77 -> allocator's 80-reg target
//  = 6 waves/EU = 24 waves/CU, free-running (no convoy).
//  FP accumulation order bit-identical to R6/R8 -> absmax 0.03125.
//  Gates: A WRITE_SIZE ~512B (spill tripwire); VGPR 72-84; occ >=60%.
//  Kernel B unchanged (near floor).

#define BT 8192        // B*T tokens
#define NC 4096        // N*C
#define NC4 1024       // NC/4
#define NT 32          // tiles
#define TD 128         // d's per tile

// ---------------- Kernel A: reduction pass -> W[tok][4][4] ----------------
__global__ __launch_bounds__(256) void lora_w_kernel(
    const float* __restrict__ x,
    const float* __restrict__ inw,
    const float* __restrict__ phi_pre,
    const float* __restrict__ phi_post,
    const float* __restrict__ phi_res,
    const float* __restrict__ b_pre,
    const float* __restrict__ b_post,
    const float* __restrict__ b_res,
    const float* __restrict__ alpha_pre,
    const float* __restrict__ alpha_post,
    const float* __restrict__ alpha_res,
    const int*   __restrict__ adapter_indices,
    float* __restrict__ wsf)
{
    const int tid = threadIdx.x;
    const int g   = tid & 3;        // token for phase 2c
    const int wvid= tid >> 6;       // wave 0..3
    const int ln  = tid & 63;       // lane within wave
    const int dl  = tid & 127;      // d-slice within tile
    const int half= tid >> 7;       // output half (wave-uniform)
    const int blk = blockIdx.x;
    const int b   = blk >> 9;       // block-uniform batch
    const int idx = adapter_indices[b];

    const float4* __restrict__ pp4 = (const float4*)(phi_pre  + (size_t)idx * (NC * 4));
    const float4* __restrict__ po4 = (const float4*)(phi_post + (size_t)idx * (NC * 4));
    const float4* __restrict__ pr4 = (const float4*)(phi_res  + (size_t)idx * (NC * 16));
    const float*  __restrict__ inwp = inw + (size_t)idx * NC + dl;      // + m*TD
    const float*  __restrict__ xb   = x + (size_t)(blk * 4) * NC + dl;  // + j*NC + m*TD

    __shared__ float red[4][4][14];   // only LDS left: cross-wave reduction

    // per-thread phi streams (wave-uniform half -> uniform branches):
    //  half0: a=pp[D], p=po[D], r=prT[0][D]=pr4[D*4]
    //  half1: a=prT[1][D], p=prT[2][D], r=prT[3][D]
    //  D = m*TD + dl  ->  index m*As etc. from bases below.
    const float4* __restrict__ Ap = half ? (pr4 + (size_t)dl * 4 + 1) : (pp4 + dl);
    const float4* __restrict__ Pp = half ? (pr4 + (size_t)dl * 4 + 2) : (po4 + dl);
    const float4* __restrict__ Rp = half ? (pr4 + (size_t)dl * 4 + 3) : (pr4 + (size_t)dl * 4);
    const int As = half ? TD * 4 : TD;
    const int Ps = half ? TD * 4 : TD;
    const int Rs = TD * 4;

    float acc[12][4];
    float ss[4];
    #pragma unroll
    for (int j = 0; j < 12; ++j) {
        acc[j][0] = 0.0f; acc[j][1] = 0.0f; acc[j][2] = 0.0f; acc[j][3] = 0.0f;
    }
    ss[0] = ss[1] = ss[2] = ss[3] = 0.0f;

    // depth-1 scalar prefetch for the HBM-latency x/w stream (R6-proven)
    float xn[4], wn;
    #pragma unroll
    for (int j = 0; j < 4; ++j) xn[j] = xb[j * NC];
    wn = inwp[0];

    // ---- Phase 1: 32 tiles, NO barriers; phi straight from L1/L2 ----
    #pragma unroll 1
    for (int m = 0; m < NT; ++m) {
        const float wv = wn;
        float s[4];
        #pragma unroll
        for (int j = 0; j < 4; ++j) {
            const float xv = xn[j];
            s[j] = xv * wv;
            ss[j] = fmaf(xv, xv, ss[j]);         // only half0's ss is consumed
        }
        if (m < NT - 1) {                        // x,w m+1 in flight during FMA
            #pragma unroll
            for (int j = 0; j < 4; ++j) xn[j] = xb[j * NC + (m + 1) * TD];
            wn = inwp[(m + 1) * TD];
        }

        const float4 a = Ap[(size_t)m * As];
        const float4 p = Pp[(size_t)m * Ps];
        const float4 r = Rp[(size_t)m * Rs];
        #pragma unroll
        for (int j = 0; j < 4; ++j) {
            acc[0][j]  = fmaf(s[j], a.x, acc[0][j]);
            acc[1][j]  = fmaf(s[j], a.y, acc[1][j]);
            acc[2][j]  = fmaf(s[j], a.z, acc[2][j]);
            acc[3][j]  = fmaf(s[j], a.w, acc[3][j]);
            acc[4][j]  = fmaf(s[j], p.x, acc[4][j]);
            acc[5][j]  = fmaf(s[j], p.y, acc[5][j]);
            acc[6][j]  = fmaf(s[j], p.z, acc[6][j]);
            acc[7][j]  = fmaf(s[j], p.w, acc[7][j]);
            acc[8][j]  = fmaf(s[j], r.x, acc[8][j]);
            acc[9][j]  = fmaf(s[j], r.y, acc[9][j]);
            acc[10][j] = fmaf(s[j], r.z, acc[10][j]);
            acc[11][j] = fmaf(s[j], r.w, acc[11][j]);
        }
    }

    // ---- Phase 2a: token-redistributing butterfly (wave sum) ----
    float t12[13];
    #define RED4(V0, V1, V2, V3, DST)                                   \
    {                                                                   \
        const float u0 = (V0) + __shfl_xor((V0), 1);                    \
        const float u1 = (V1) + __shfl_xor((V1), 1);                    \
        const float u2 = (V2) + __shfl_xor((V2), 1);                    \
        const float u3 = (V3) + __shfl_xor((V3), 1);                    \
        const float r0 = (ln & 1) ? u1 : u0;                            \
        const float r1 = (ln & 1) ? u3 : u2;                            \
        const float w0 = r0 + __shfl_xor(r0, 2);                        \
        const float w1 = r1 + __shfl_xor(r1, 2);                        \
        float tv = (ln & 2) ? w1 : w0;                                  \
        tv += __shfl_xor(tv, 4);  tv += __shfl_xor(tv, 8);              \
        tv += __shfl_xor(tv, 16); tv += __shfl_xor(tv, 32);             \
        (DST) = tv;                                                     \
    }
    #pragma unroll
    for (int j = 0; j < 12; ++j)
        RED4(acc[j][0], acc[j][1], acc[j][2], acc[j][3], t12[j]);
    RED4(ss[0], ss[1], ss[2], ss[3], t12[12]);
    #undef RED4

    // ---- Phase 2b: cross-wave/-half assembly via LDS ----
    if (ln < 4) {
        #pragma unroll
        for (int j = 0; j < 13; ++j) red[wvid][ln][j] = t12[j];
    }
    __syncthreads();
    float tot[25];
    #pragma unroll
    for (int j = 0; j < 12; ++j) {
        tot[j]      = red[0][g][j] + red[1][g][j];
        tot[12 + j] = red[2][g][j] + red[3][g][j];
    }
    tot[24] = red[0][g][12] + red[1][g][12];

    // ---- Phase 2c: rms, gates, sinkhorn (token g per thread) ----
    const float inv_rms = rsqrtf(tot[24] * (1.0f / 4096.0f) + 1e-5f);
    const float apre  = alpha_pre[idx];
    const float apost = alpha_post[idx];
    const float ares  = alpha_res[idx];

    float Hpre[4], Hpost[4];
    #pragma unroll
    for (int n = 0; n < 4; ++n) {
        const float zp = fmaf(apre,  tot[n]     * inv_rms, b_pre[idx * 4 + n]);
        Hpre[n]  = 1.0f / (1.0f + __expf(-zp));
        const float zq = fmaf(apost, tot[4 + n] * inv_rms, b_post[idx * 4 + n]);
        Hpost[n] = 2.0f / (1.0f + __expf(-zq));
    }

    // lane owns element (si,sj) of token g's 4x4 matrix
    const int s16 = ln >> 2;         // 0..15
    const int sj = s16 & 3;
    const int si = s16 >> 2;
    float Mv = __expf(fmaf(ares, tot[8 + si * 4 + sj] * inv_rms,
                           b_res[idx * 16 + si * 4 + sj]));
    #pragma unroll
    for (int it = 0; it < 20; ++it) {
        float rs = Mv + __shfl_xor(Mv, 4);   // sum over j (lane bits 2,3)
        rs += __shfl_xor(rs, 8);
        Mv *= __builtin_amdgcn_rcpf(rs);
        float cs = Mv + __shfl_xor(Mv, 16);  // sum over i (lane bits 4,5)
        cs += __shfl_xor(cs, 32);
        Mv *= __builtin_amdgcn_rcpf(cs);
    }

    // ---- write W[tok][si][sj] = M + Hpost[si]*Hpre[sj] (wave 0 only) ----
    // select-chains keep Hpre/Hpost register indices static (rule #20).
    if (wvid == 0) {
        const float hpo = (si == 0) ? Hpost[0] : (si == 1) ? Hpost[1]
                        : (si == 2) ? Hpost[2] : Hpost[3];
        const float hpr = (sj == 0) ? Hpre[0]  : (sj == 1) ? Hpre[1]
                        : (sj == 2) ? Hpre[2]  : Hpre[3];
        wsf[(size_t)blk * 64 + g * 16 + si * 4 + sj] = fmaf(hpo, hpr, Mv);
    }
}

// ---------------- Kernel B: streaming mix  out = W . x ----------------
__global__ __launch_bounds__(256) void lora_mix_kernel(
    const float* __restrict__ x,
    const float* __restrict__ wsf,
    float* __restrict__ out)
{
    const int tok = blockIdx.x;
    const int c4  = threadIdx.x;            // 0..255 column-of-float4

    const float4* __restrict__ x4p = (const float4*)x   + (size_t)tok * NC4;
    float4* __restrict__       out4 = (float4*)out      + (size_t)tok * NC4;
    const float4* __restrict__ w4   = (const float4*)wsf + (size_t)tok * 4;

    // W rows: same address across the wave -> broadcast loads
    const float4 W0 = w4[0];
    const float4 W1 = w4[1];
    const float4 W2 = w4[2];
    const float4 W3 = w4[3];

    const float4 x0 = x4p[0 * 256 + c4];
    const float4 x1 = x4p[1 * 256 + c4];
    const float4 x2 = x4p[2 * 256 + c4];
    const float4 x3 = x4p[3 * 256 + c4];

    // identical FMA chain order to the fused version (bitwise-stable)
    #define MIXROW(WR, DSTIDX)                                                    \
    {                                                                             \
        float4 o;                                                                 \
        o.x = fmaf(WR.x, x0.x, fmaf(WR.y, x1.x, fmaf(WR.z, x2.x, WR.w * x3.x)));  \
        o.y = fmaf(WR.x, x0.y, fmaf(WR.y, x1.y, fmaf(WR.z, x2.y, WR.w * x3.y)));  \
        o.z = fmaf(WR.x, x0.z, fmaf(WR.y, x1.z, fmaf(WR.z, x2.z, WR.w * x3.z)));  \
        o.w = fmaf(WR.x, x0.w, fmaf(WR.y, x1.w, fmaf(WR.z, x2.w, WR.w * x3.w)));  \
        out4[(DSTIDX) * 256 + c4] = o;                                            \
    }
    MIXROW(W0, 0);
    MIXROW(W1, 1);
    MIXROW(W2, 2);
    MIXROW(W3, 3);
    #undef MIXROW
}

extern "C" void kernel_launch(void* const* d_in, const int* in_sizes, int n_in,
                              void* d_out, int out_size, void* d_ws, size_t ws_size,
                              hipStream_t stream) {
    const float* x         = (const float*)d_in[0];
    const float* inw       = (const float*)d_in[1];
    const float* phi_pre   = (const float*)d_in[2];
    const float* phi_post  = (const float*)d_in[3];
    const float* phi_res   = (const float*)d_in[4];
    const float* b_pre     = (const float*)d_in[5];
    const float* b_post    = (const float*)d_in[6];
    const float* b_res     = (const float*)d_in[7];
    const float* alpha_pre = (const float*)d_in[8];
    const float* alpha_post= (const float*)d_in[9];
    const float* alpha_res = (const float*)d_in[10];
    const int*   adapter   = (const int*)d_in[11];
    float* out = (float*)d_out;
    float* wsf = (float*)d_ws;               // 8192 * 16 floats = 512 KB

    dim3 block(256);
    lora_w_kernel<<<dim3(BT / 4), block, 0, stream>>>(
        x, inw, phi_pre, phi_post, phi_res,
        b_pre, b_post, b_res,
        alpha_pre, alpha_post, alpha_res,
        adapter, wsf);
    lora_mix_kernel<<<dim3(BT), block, 0, stream>>>(x, wsf, out);
}

// Round 10
// 323.566 us; speedup vs baseline: 1.0555x; 1.0555x over previous
//
#include <hip/hip_runtime.h>

// LoRAConnector: B=4, T=2048, N=4, C=1024, A=8, nC=4096, SINKHORN_ITERS=20
//
// Round 11: 4x workgroup parallelism (d-split) + finalize folded into mix.
//  R9 post-mortem: barrier-free/cache-direct phi = 131us > staged 104us
//  (VGPR clamped to 48, phi L2 latency exposed per-iter). Staged A wins.
//  Standing mystery: every structure is 70-88% idle. The never-varied
//  variable: grid = 2048 blocks = EXACTLY 1.0x machine capacity -> zero
//  oversubscription; block-level serialization (32 barrier rounds/block)
//  becomes raw idle. Fix: split the d-reduction into 4 chunk-blocks
//  (NT=8 tiles each, inner loop = R8-A verbatim), grid 8192 = 4x
//  parallelism, 4x shorter per-block chains. Chunk-blocks write 25
//  partials/token to ws (3.4MB). Sinkhorn+gates move into kernel B's
//  wave 0, computed in LDS WHILE the block's x loads are in HBM flight
//  (free overlap), then 4 waves mix. Two dispatches total.
//  FP note: cross-chunk partial sums reorder accumulation (first reorder
//  this session) -> absmax may drift from 0.03125. Revert to R6 on fail.
//  Gates: partial kernel 45-65us (if >=90: parallelism wasn't the limiter
//  -> structure ceiling); WRITE(A) ~3.4MB (spill tripwire vs 131072KB-scale);
//  mix ~40-48us near floor.

#define BT 8192        // B*T tokens
#define NC 4096        // N*C
#define NC4 1024       // NC/4
#define NTC 8          // tiles per chunk
#define TD 128         // d's per tile

// ---------- Kernel A: partial reduction per (token-group, d-chunk) ----------
__global__ __launch_bounds__(256) void lora_partial_kernel(
    const float* __restrict__ x,
    const float* __restrict__ inw,
    const float* __restrict__ phi_pre,
    const float* __restrict__ phi_post,
    const float* __restrict__ phi_res,
    const int*   __restrict__ adapter_indices,
    float* __restrict__ wsf)
{
    const int tid = threadIdx.x;
    const int wvid= tid >> 6;       // wave 0..3
    const int ln  = tid & 63;       // lane within wave
    const int dl  = tid & 127;      // d-slice within tile
    const int half= tid >> 7;       // output half (wave-uniform)
    const int blk = blockIdx.x;
    const int chunk = blk >> 11;    // 0..3: which quarter of d
    const int tg    = blk & 2047;   // token group (4 tokens)
    const int b   = tg >> 9;        // batch
    const int idx = adapter_indices[b];

    // phi bases pre-offset to this chunk's d-window
    const float4* __restrict__ pp4 = (const float4*)(phi_pre  + (size_t)idx * (NC * 4))  + (size_t)chunk * 1024;
    const float4* __restrict__ po4 = (const float4*)(phi_post + (size_t)idx * (NC * 4))  + (size_t)chunk * 1024;
    const float4* __restrict__ pr4 = (const float4*)(phi_res  + (size_t)idx * (NC * 16)) + (size_t)chunk * 4096;
    const float*  __restrict__ inwp = inw + (size_t)idx * NC + chunk * 1024 + dl;
    const float*  __restrict__ xb   = x + (size_t)(tg * 4) * NC + chunk * 1024 + dl;

    // double-buffered phi tile, 768 float4 = 12KB per buffer:
    //  [0..127]=pp[d], [128..255]=po[d], [256+q*128+d]=prT[q][d]
    __shared__ float4 tileL[2][768];
    __shared__ float red[4][4][14];

    // staging: 12 chunks of 1KB per tile; wave wvid owns chunks 3*wvid..+2.
    // dest = tileL[bf][c*64+ln] (linear, global_load_lds requirement);
    // phi_res transposed via per-lane SOURCE address (m173): k=c-4, q=k>>1,
    // subd=(k&1)*64+ln, src=pr4[subd*4+q] -> lands at prT[q][subd].
    const float4* sg[3];
    int sstr[3];
    #pragma unroll
    for (int i = 0; i < 3; ++i) {
        const int c = wvid * 3 + i;              // wave-uniform
        const float4* bp; int off, str;
        if (c < 4) {
            bp  = (c < 2) ? pp4 : po4;
            off = ((c & 1) << 6) + ln;
            str = TD;                            // 128 float4 per tile
        } else {
            const int k = c - 4;
            bp  = pr4;
            off = ((((k & 1) << 6) + ln) << 2) + (k >> 1);
            str = TD * 4;                        // 512 float4 per tile
        }
        sg[i] = bp + off;
        sstr[i] = str;
    }

    #define STAGE_TILE(MT, BF)                                                   \
    {                                                                            \
        _Pragma("unroll")                                                        \
        for (int i = 0; i < 3; ++i) {                                            \
            __builtin_amdgcn_global_load_lds(                                    \
                (const __attribute__((address_space(1))) void*)(sg[i] + (size_t)(MT) * sstr[i]), \
                (__attribute__((address_space(3))) void*)&tileL[BF][((wvid * 3 + i) << 6) + ln], \
                16, 0, 0);                                                       \
        }                                                                        \
    }

    // ---- Prologue: stage tile 0; prefetch x,w for tile 0 ----
    STAGE_TILE(0, 0);

    float acc[12][4];
    float ss[4];
    #pragma unroll
    for (int j = 0; j < 12; ++j) {
        acc[j][0] = 0.0f; acc[j][1] = 0.0f; acc[j][2] = 0.0f; acc[j][3] = 0.0f;
    }
    ss[0] = ss[1] = ss[2] = ss[3] = 0.0f;

    float xn[4], wn;
    #pragma unroll
    for (int j = 0; j < 4; ++j) xn[j] = xb[j * NC];
    wn = inwp[0];

    const int ba = half * 384 + dl;  // this thread's 3 reads: ba, ba+128, ba+256

    // ---- Phase 1: 8 tiles; barrier -> stage next -> consume current ----
    #pragma unroll 1
    for (int m = 0; m < NTC; ++m) {
        const int bf = m & 1;
        __syncthreads();                         // tile m resident (vmcnt drain)
        if (m < NTC - 1) STAGE_TILE(m + 1, bf ^ 1);  // phi m+1 in flight

        const float wv = wn;
        float s[4];
        #pragma unroll
        for (int j = 0; j < 4; ++j) {
            const float xv = xn[j];
            s[j] = xv * wv;
            ss[j] = fmaf(xv, xv, ss[j]);         // only half0's ss is consumed
        }
        if (m < NTC - 1) {                       // x,w m+1 in flight
            #pragma unroll
            for (int j = 0; j < 4; ++j) xn[j] = xb[j * NC + (m + 1) * TD];
            wn = inwp[(m + 1) * TD];
        }

        const float4 a = tileL[bf][ba];          // half0: pp[d]   half1: prT[1][d]
        const float4 p = tileL[bf][ba + 128];    // half0: po[d]   half1: prT[2][d]
        const float4 r = tileL[bf][ba + 256];    // half0: prT[0]  half1: prT[3][d]
        #pragma unroll
        for (int j = 0; j < 4; ++j) {
            acc[0][j]  = fmaf(s[j], a.x, acc[0][j]);
            acc[1][j]  = fmaf(s[j], a.y, acc[1][j]);
            acc[2][j]  = fmaf(s[j], a.z, acc[2][j]);
            acc[3][j]  = fmaf(s[j], a.w, acc[3][j]);
            acc[4][j]  = fmaf(s[j], p.x, acc[4][j]);
            acc[5][j]  = fmaf(s[j], p.y, acc[5][j]);
            acc[6][j]  = fmaf(s[j], p.z, acc[6][j]);
            acc[7][j]  = fmaf(s[j], p.w, acc[7][j]);
            acc[8][j]  = fmaf(s[j], r.x, acc[8][j]);
            acc[9][j]  = fmaf(s[j], r.y, acc[9][j]);
            acc[10][j] = fmaf(s[j], r.z, acc[10][j]);
            acc[11][j] = fmaf(s[j], r.w, acc[11][j]);
        }
    }

    // ---- Phase 2a: token-redistributing butterfly (wave sum) ----
    float t12[13];
    #define RED4(V0, V1, V2, V3, DST)                                   \
    {                                                                   \
        const float u0 = (V0) + __shfl_xor((V0), 1);                    \
        const float u1 = (V1) + __shfl_xor((V1), 1);                    \
        const float u2 = (V2) + __shfl_xor((V2), 1);                    \
        const float u3 = (V3) + __shfl_xor((V3), 1);                    \
        const float r0 = (ln & 1) ? u1 : u0;                            \
        const float r1 = (ln & 1) ? u3 : u2;                            \
        const float w0 = r0 + __shfl_xor(r0, 2);                        \
        const float w1 = r1 + __shfl_xor(r1, 2);                        \
        float tv = (ln & 2) ? w1 : w0;                                  \
        tv += __shfl_xor(tv, 4);  tv += __shfl_xor(tv, 8);              \
        tv += __shfl_xor(tv, 16); tv += __shfl_xor(tv, 32);             \
        (DST) = tv;                                                     \
    }
    #pragma unroll
    for (int j = 0; j < 12; ++j)
        RED4(acc[j][0], acc[j][1], acc[j][2], acc[j][3], t12[j]);
    RED4(ss[0], ss[1], ss[2], ss[3], t12[12]);
    #undef RED4

    // ---- Phase 2b: cross-wave assembly + partial write ----
    if (ln < 4) {
        #pragma unroll
        for (int j = 0; j < 13; ++j) red[wvid][ln][j] = t12[j];
    }
    __syncthreads();
    // 25 partials per token: [0..12] = half0 (12 acc + ss), [13..24] = half1.
    if (tid < 100) {
        const int gg = tid / 25;
        const int j  = tid % 25;
        const float v = (j < 13) ? (red[0][gg][j] + red[1][gg][j])
                                 : (red[2][gg][j - 13] + red[3][gg][j - 13]);
        wsf[((size_t)(tg * 4 + gg) * 4 + chunk) * 26 + j] = v;
    }
    #undef STAGE_TILE
}

// ------- Kernel B: finalize (W in wave 0, overlapped with x flight) + mix -------
__global__ __launch_bounds__(256) void lora_mix_kernel(
    const float* __restrict__ x,
    const float* __restrict__ wsf,
    const float* __restrict__ b_pre,
    const float* __restrict__ b_post,
    const float* __restrict__ b_res,
    const float* __restrict__ alpha_pre,
    const float* __restrict__ alpha_post,
    const float* __restrict__ alpha_res,
    const int*   __restrict__ adapter_indices,
    float* __restrict__ out)
{
    const int tok = blockIdx.x;
    const int tid = threadIdx.x;            // 0..255 column-of-float4

    const float4* __restrict__ x4p = (const float4*)x + (size_t)tok * NC4;
    float4* __restrict__       out4 = (float4*)out    + (size_t)tok * NC4;

    __shared__ float4 Wl4[4];

    // x loads issued up-front: HBM flight overlaps wave 0's finalize work.
    const float4 x0 = x4p[0 * 256 + tid];
    const float4 x1 = x4p[1 * 256 + tid];
    const float4 x2 = x4p[2 * 256 + tid];
    const float4 x3 = x4p[3 * 256 + tid];

    if (tid < 64) {
        // 4 lanes per element rj (redundant copies keep the shfl lattice intact)
        const int rj = tid >> 2;             // 0..15 = si*4+sj
        const int sj = rj & 3;
        const int si = rj >> 2;
        const int idx = adapter_indices[tok >> 11];
        const float* __restrict__ base = wsf + (size_t)tok * 104;  // 4 chunks x 26
        const int rslot = (rj < 4) ? (8 + rj) : (9 + rj);
        float pre_s = 0.0f, post_s = 0.0f, res_s = 0.0f, ss_s = 0.0f;
        #pragma unroll
        for (int c = 0; c < 4; ++c) {
            pre_s  += base[c * 26 + sj];
            post_s += base[c * 26 + 4 + si];
            res_s  += base[c * 26 + rslot];
            ss_s   += base[c * 26 + 12];
        }
        const float inv_rms = rsqrtf(ss_s * (1.0f / 4096.0f) + 1e-5f);
        const float Hpre_j  = 1.0f / (1.0f + __expf(-fmaf(alpha_pre[idx],  pre_s  * inv_rms, b_pre[idx * 4 + sj])));
        const float Hpost_i = 2.0f / (1.0f + __expf(-fmaf(alpha_post[idx], post_s * inv_rms, b_post[idx * 4 + si])));
        float Mv = __expf(fmaf(alpha_res[idx], res_s * inv_rms, b_res[idx * 16 + rj]));
        #pragma unroll
        for (int it = 0; it < 20; ++it) {
            float rs = Mv + __shfl_xor(Mv, 4);   // sum over sj (lane bits 2,3)
            rs += __shfl_xor(rs, 8);
            Mv *= __builtin_amdgcn_rcpf(rs);
            float cs = Mv + __shfl_xor(Mv, 16);  // sum over si (lane bits 4,5)
            cs += __shfl_xor(cs, 32);
            Mv *= __builtin_amdgcn_rcpf(cs);
        }
        if ((tid & 3) == 0)
            ((float*)Wl4)[rj] = fmaf(Hpost_i, Hpre_j, Mv);
    }
    __syncthreads();

    const float4 W0 = Wl4[0];
    const float4 W1 = Wl4[1];
    const float4 W2 = Wl4[2];
    const float4 W3 = Wl4[3];

    #define MIXROW(WR, DSTIDX)                                                    \
    {                                                                             \
        float4 o;                                                                 \
        o.x = fmaf(WR.x, x0.x, fmaf(WR.y, x1.x, fmaf(WR.z, x2.x, WR.w * x3.x)));  \
        o.y = fmaf(WR.x, x0.y, fmaf(WR.y, x1.y, fmaf(WR.z, x2.y, WR.w * x3.y)));  \
        o.z = fmaf(WR.x, x0.z, fmaf(WR.y, x1.z, fmaf(WR.z, x2.z, WR.w * x3.z)));  \
        o.w = fmaf(WR.x, x0.w, fmaf(WR.y, x1.w, fmaf(WR.z, x2.w, WR.w * x3.w)));  \
        out4[(DSTIDX) * 256 + tid] = o;                                           \
    }
    MIXROW(W0, 0);
    MIXROW(W1, 1);
    MIXROW(W2, 2);
    MIXROW(W3, 3);
    #undef MIXROW
}

extern "C" void kernel_launch(void* const* d_in, const int* in_sizes, int n_in,
                              void* d_out, int out_size, void* d_ws, size_t ws_size,
                              hipStream_t stream) {
    const float* x         = (const float*)d_in[0];
    const float* inw       = (const float*)d_in[1];
    const float* phi_pre   = (const float*)d_in[2];
    const float* phi_post  = (const float*)d_in[3];
    const float* phi_res   = (const float*)d_in[4];
    const float* b_pre     = (const float*)d_in[5];
    const float* b_post    = (const float*)d_in[6];
    const float* b_res     = (const float*)d_in[7];
    const float* alpha_pre = (const float*)d_in[8];
    const float* alpha_post= (const float*)d_in[9];
    const float* alpha_res = (const float*)d_in[10];
    const int*   adapter   = (const int*)d_in[11];
    float* out = (float*)d_out;
    float* wsf = (float*)d_ws;               // 8192 tokens * 104 floats = 3.41 MB

    dim3 block(256);
    lora_partial_kernel<<<dim3(BT * 4 / 4), block, 0, stream>>>(   // 8192 blocks
        x, inw, phi_pre, phi_post, phi_res, adapter, wsf);
    lora_mix_kernel<<<dim3(BT), block, 0, stream>>>(
        x, wsf, b_pre, b_post, b_res,
        alpha_pre, alpha_post, alpha_res, adapter, out);
}